// Round 11
// baseline (99.449 us; speedup 1.0000x reference)
//
#include <hip/hip_runtime.h>
#include <hip/hip_bf16.h>

using bf16x8 = __attribute__((ext_vector_type(8))) short;
using f32x4  = __attribute__((ext_vector_type(4))) float;
using f32x16 = __attribute__((ext_vector_type(16))) float;
using u32x4  = __attribute__((ext_vector_type(4))) unsigned;

__device__ __forceinline__ short f2bf(float f) {
  union { float f; unsigned u; } v; v.f = f;
  unsigned r = (v.u + 0x7FFFu + ((v.u >> 16) & 1u)) >> 16;
  return (short)(unsigned short)r;
}

__device__ __forceinline__ unsigned cvtpk(float lo, float hi) {
  unsigned r;
  asm("v_cvt_pk_bf16_f32 %0, %1, %2" : "=v"(r) : "v"(lo), "v"(hi));
  return r;
}

__device__ __forceinline__ void plswap(unsigned &a, unsigned &b) {
  asm("v_permlane32_swap_b32 %0, %1" : "+v"(a), "+v"(b));
}

#define GLLDS(gp, lp) __builtin_amdgcn_global_load_lds(                        \
    (const __attribute__((address_space(1))) void*)(gp),                       \
    (__attribute__((address_space(3))) void*)(lp), 16, 0, 0)

// ---------------- fp32 -> bf16 conversion (8 elems/thread) -----------------
__global__ __launch_bounds__(256)
void cvt_f32_bf16(const float* __restrict__ in, short* __restrict__ out, int n8)
{
  int i = blockIdx.x * 256 + threadIdx.x;
  if (i >= n8) return;
  float4 lo = *(const float4*)(in + (size_t)i * 8);
  float4 hi = *(const float4*)(in + (size_t)i * 8 + 4);
  uint4 r;
  r.x = cvtpk(lo.x, lo.y);
  r.y = cvtpk(lo.z, lo.w);
  r.z = cvtpk(hi.x, hi.y);
  r.w = cvtpk(hi.z, hi.w);
  *(uint4*)(out + (size_t)i * 8) = r;
}

// ---------------- QKV projection (unchanged) -------------------------------
__global__ __launch_bounds__(256, 2)
void gemm_qkv(const short* __restrict__ A, const short* __restrict__ B,
              short* __restrict__ outQ, short* __restrict__ outK,
              short* __restrict__ outVt, const float* __restrict__ temp)
{
  __shared__ short As[128 * 32];
  __shared__ short Bs[128 * 32];
  const int Kd = 512;
  const int tid  = threadIdx.x;
  const int lane = tid & 63;
  const int w    = tid >> 6;
  const int wr   = w >> 1, wc = w & 1;
  const int fr   = lane & 15, fq = lane >> 4;
  const int bm = blockIdx.y, bn = blockIdx.x;
  const int rowA = bm * 128, rowB = bn * 128;

  const int lrow   = lane >> 2;
  const int lchunk = ((lane & 3) ^ ((lane >> 3) & 3)) * 8;
  const short* gA0 = A + (size_t)(rowA + w * 32 + lrow) * Kd + lchunk;
  const short* gB0 = B + (size_t)(rowB + w * 32 + lrow) * Kd + lchunk;
  char* lA0 = (char*)As + (w * 32) * 64;
  char* lB0 = (char*)Bs + (w * 32) * 64;
  const int rxor = ((fr >> 1) & 3) << 4;

  f32x4 acc[4][4];
  #pragma unroll
  for (int m = 0; m < 4; ++m)
    #pragma unroll
    for (int n = 0; n < 4; ++n) acc[m][n] = (f32x4){0.f, 0.f, 0.f, 0.f};

  for (int k0 = 0; k0 < Kd; k0 += 32) {
    GLLDS(gA0 + k0,            lA0);
    GLLDS(gA0 + k0 + 16 * Kd,  lA0 + 1024);
    GLLDS(gB0 + k0,            lB0);
    GLLDS(gB0 + k0 + 16 * Kd,  lB0 + 1024);
    __syncthreads();
    bf16x8 afr[4], bfr[4];
    #pragma unroll
    for (int m = 0; m < 4; ++m)
      afr[m] = *(const bf16x8*)((char*)As + (wr*64 + m*16 + fr) * 64 + ((fq*16) ^ rxor));
    #pragma unroll
    for (int n = 0; n < 4; ++n)
      bfr[n] = *(const bf16x8*)((char*)Bs + (wc*64 + n*16 + fr) * 64 + ((fq*16) ^ rxor));
    #pragma unroll
    for (int m = 0; m < 4; ++m)
      #pragma unroll
      for (int n = 0; n < 4; ++n)
        acc[m][n] = __builtin_amdgcn_mfma_f32_16x16x32_bf16(afr[m], bfr[n], acc[m][n], 0, 0, 0);
    __syncthreads();
  }

  const int gc0   = rowB + wc*64;
  const int slice = gc0 >> 6;
  const int t3    = slice >> 3;
  const int h     = slice & 7;
  if (t3 < 2) {
    float scl[4][4];
    const float tval = (t3 == 0) ? temp[h] * 1.44269504088896f : 1.0f;
    #pragma unroll
    for (int m = 0; m < 4; ++m) {
      #pragma unroll
      for (int r = 0; r < 4; ++r) {
        float ss = 0.f;
        #pragma unroll
        for (int n = 0; n < 4; ++n) ss += acc[m][n][r] * acc[m][n][r];
        #pragma unroll
        for (int off = 1; off < 16; off <<= 1) ss += __shfl_xor(ss, off);
        scl[m][r] = tval / fmaxf(sqrtf(ss), 1e-12f);
      }
    }
    short* dst = (t3 == 0) ? outQ : outK;
    #pragma unroll
    for (int m = 0; m < 4; ++m) {
      #pragma unroll
      for (int r = 0; r < 4; ++r) {
        int rg = rowA + wr*64 + m*16 + fq*4 + r;
        int b = rg >> 11, nn = rg & 2047;
        size_t rowoff = ((size_t)(b*8 + h) * 2048 + nn) * 64;
        #pragma unroll
        for (int n = 0; n < 4; ++n)
          dst[rowoff + n*16 + fr] = f2bf(acc[m][n][r] * scl[m][r]);
      }
    }
  } else {
    #pragma unroll
    for (int m = 0; m < 4; ++m) {
      #pragma unroll
      for (int r = 0; r < 4; ++r) {
        int rg = rowA + wr*64 + m*16 + fq*4 + r;
        int b = rg >> 11, nn = rg & 2047;
        #pragma unroll
        for (int n = 0; n < 4; ++n)
          outVt[((size_t)(b*8 + h) * 64 + n*16 + fr) * 2048 + nn] = f2bf(acc[m][n][r]);
      }
    }
  }
}

// ---------------- output projection: 128x64 tiles (2 blocks/CU) ------------
__global__ __launch_bounds__(256, 2)
void gemm_out(const short* __restrict__ A, const short* __restrict__ B,
              float* __restrict__ outC)
{
  __shared__ short As[128 * 32];
  __shared__ short Bs[64 * 32];
  const int Kd = 512, N = 512;
  const int tid  = threadIdx.x;
  const int lane = tid & 63;
  const int w    = tid >> 6;
  const int fr   = lane & 15, fq = lane >> 4;
  const int bm = blockIdx.y, bn = blockIdx.x;
  const int rowA = bm * 128, rowB = bn * 64;

  const int lrow   = lane >> 2;
  const int lchunk = ((lane & 3) ^ ((lane >> 3) & 3)) * 8;
  const short* gA0 = A + (size_t)(rowA + w * 32 + lrow) * Kd + lchunk;
  const short* gB0 = B + (size_t)(rowB + w * 16 + lrow) * Kd + lchunk;
  char* lA0 = (char*)As + (w * 32) * 64;
  char* lB0 = (char*)Bs + (w * 16) * 64;
  const int rxor = ((fr >> 1) & 3) << 4;

  f32x4 acc[2][4];
  #pragma unroll
  for (int m = 0; m < 2; ++m)
    #pragma unroll
    for (int n = 0; n < 4; ++n) acc[m][n] = (f32x4){0.f, 0.f, 0.f, 0.f};

  for (int k0 = 0; k0 < Kd; k0 += 32) {
    GLLDS(gA0 + k0,            lA0);
    GLLDS(gA0 + k0 + 16 * Kd,  lA0 + 1024);
    GLLDS(gB0 + k0,            lB0);
    __syncthreads();
    bf16x8 afr[2], bfr[4];
    #pragma unroll
    for (int m = 0; m < 2; ++m)
      afr[m] = *(const bf16x8*)((char*)As + (w*32 + m*16 + fr) * 64 + ((fq*16) ^ rxor));
    #pragma unroll
    for (int n = 0; n < 4; ++n)
      bfr[n] = *(const bf16x8*)((char*)Bs + (n*16 + fr) * 64 + ((fq*16) ^ rxor));
    #pragma unroll
    for (int m = 0; m < 2; ++m)
      #pragma unroll
      for (int n = 0; n < 4; ++n)
        acc[m][n] = __builtin_amdgcn_mfma_f32_16x16x32_bf16(afr[m], bfr[n], acc[m][n], 0, 0, 0);
    __syncthreads();
  }

  #pragma unroll
  for (int m = 0; m < 2; ++m) {
    int r0 = rowA + w*32 + m*16 + fq*4;
    #pragma unroll
    for (int n = 0; n < 4; ++n) {
      int c = rowB + n*16 + fr;
      #pragma unroll
      for (int r = 0; r < 4; ++r)
        outC[(size_t)(r0 + r) * N + c] = acc[m][n][r];
    }
  }
}

// ---------------- flash attention v4: k-partitioned waves, barrier-free ----
// Block = 64 q-rows shared by 4 waves; each wave owns k-tiles w, w+4, ...
// (32 k-rows each) in wave-PRIVATE double-buffered LDS -> no K/V frag-read
// redundancy across waves, zero barriers in the k-loop. Static-max softmax
// makes per-wave partial (O,l) additive; one LDS reduction at the end
// (reusing the staging buffers). LDS 65KB -> 2 blocks/CU.
__global__ __launch_bounds__(256, 2)
void attn_fwd(const short* __restrict__ Q, const short* __restrict__ Kt,
              const short* __restrict__ Vt, short* __restrict__ AO,
              const float* __restrict__ temp)
{
  __shared__ short SKV[4 * 2 * 4096];   // 4 waves x 2 bufs x (K 4KB + V 4KB)
  __shared__ float Lsl[4][64];
  const int tid  = threadIdx.x;
  const int lane = tid & 63;
  const int w    = tid >> 6;
  const int l31  = lane & 31;
  const int hi   = lane >> 5;
  const int bh = blockIdx.x;          // XCD = bh%8
  const int qt = blockIdx.y;
  const int b = bh >> 3, h = bh & 7;
  const size_t base  = (size_t)bh * 2048 * 64;
  const size_t vbase = (size_t)bh * 64 * 2048;
  const int q0 = qt * 64;

  const short* kp = Kt + base;
  const short* vp = Vt + vbase;

  // staging maps (wave-private tile: K 32rows x 128B, V 64rows x 64B)
  const int swzK  = (((lane & 7) ^ ((lane >> 3) & 7)) << 4);
  const int vswzW = (((lane & 3) ^ ((lane >> 2) & 3)) << 4);
  const int kswz  = (l31 & 7) << 4;   // frag-read XOR for K (128B rows)
  const int vswz  = (l31 & 3) << 4;   // frag-read XOR for V (64B rows)

  char* mybuf0 = (char*)SKV + (w * 2) * 8192;

  bf16x8 sgK[4], sgV[4];
  #define ISSUE(KT)                                                                 \
    do { int kb_ = (KT) * 2048;                                                     \
      _Pragma("unroll")                                                             \
      for (int i_ = 0; i_ < 4; ++i_)                                                \
        sgK[i_] = *(const bf16x8*)(kp + kb_ + i_*512 + lane*8);                     \
      _Pragma("unroll")                                                             \
      for (int i_ = 0; i_ < 4; ++i_)                                                \
        sgV[i_] = *(const bf16x8*)(vp + (size_t)(i_*16 + (lane>>2)) * 2048          \
                                      + (KT)*32 + (lane&3)*8);                      \
    } while (0)
  #define WRITEB(P_)                                                                \
    do { char* b_ = mybuf0 + (P_) * 8192;                                           \
      _Pragma("unroll")                                                             \
      for (int i_ = 0; i_ < 4; ++i_)                                                \
        *(bf16x8*)(b_ + (i_*8 + (lane>>3)) * 128 + swzK) = sgK[i_];                 \
      _Pragma("unroll")                                                             \
      for (int i_ = 0; i_ < 4; ++i_)                                                \
        *(bf16x8*)(b_ + 4096 + (i_*16 + (lane>>2)) * 64 + vswzW) = sgV[i_];         \
    } while (0)

  // Q fragments: 2 q-groups of 32 rows each, held in regs for the whole kernel
  bf16x8 bq[2][4];
  #pragma unroll
  for (int qg = 0; qg < 2; ++qg)
    #pragma unroll
    for (int dj = 0; dj < 4; ++dj)
      bq[qg][dj] = *(const bf16x8*)(Q + base + (size_t)(q0 + qg*32 + l31) * 64 + dj*16 + hi*8);

  // static softmax max (Cauchy-Schwarz): s <= |temp|*log2e
  const float Mh = fabsf(temp[h]) * 1.44269504088896f;
  f32x16 cinit;
  #pragma unroll
  for (int r = 0; r < 16; ++r) cinit[r] = -Mh;

  f32x16 o[2][2];   // [qg][td] partial O over this wave's k-subset
  #pragma unroll
  for (int qg = 0; qg < 2; ++qg)
    #pragma unroll
    for (int td = 0; td < 2; ++td)
      #pragma unroll
      for (int r = 0; r < 16; ++r) o[qg][td][r] = 0.f;
  float lp0 = 0.f, lp1 = 0.f;

  // prologue: tile0 (kt=w) -> buf0; tile1 (kt=w+4) -> regs
  ISSUE(w);
  WRITEB(0);
  ISSUE(w + 4);

  #pragma unroll 2
  for (int j = 0; j < 16; ++j) {
    const int cur = j & 1;
    // move tile j+1 regs -> other buffer; issue loads for tile j+2
    if (j < 15) {
      WRITEB(cur ^ 1);
      if (j < 14) ISSUE(w + 4 * (j + 2));
    }
    const char* kl = mybuf0 + cur * 8192;
    const char* vl = kl + 4096;

    // QK^T (swapped, 32x32): A = K rows (k = l31 of this tile), B = Q rows
    f32x16 s0 = cinit, s1 = cinit;
    #pragma unroll
    for (int dj = 0; dj < 4; ++dj) {
      bf16x8 ak = *(const bf16x8*)(kl + l31 * 128 + ((dj*32 + hi*16) ^ kswz));
      s0 = __builtin_amdgcn_mfma_f32_32x32x16_bf16(ak, bq[0][dj], s0, 0, 0, 0);
      s1 = __builtin_amdgcn_mfma_f32_32x32x16_bf16(ak, bq[1][dj], s1, 0, 0, 0);
    }
    // P = exp2(s - M); lane-partial denominators
    #pragma unroll
    for (int r = 0; r < 16; ++r) {
      float p0 = __builtin_amdgcn_exp2f(s0[r]);
      float p1 = __builtin_amdgcn_exp2f(s1[r]);
      s0[r] = p0; s1[r] = p1;
      lp0 += p0; lp1 += p1;
    }
    // pack P -> A-frags in-register (cvt_pk + permlane32_swap)
    bf16x8 pa[2][2];
    #pragma unroll
    for (int kj = 0; kj < 2; ++kj) {
      {
        unsigned w0 = cvtpk(s0[8*kj+0], s0[8*kj+1]);
        unsigned w2 = cvtpk(s0[8*kj+4], s0[8*kj+5]);
        unsigned w1 = cvtpk(s0[8*kj+2], s0[8*kj+3]);
        unsigned w3 = cvtpk(s0[8*kj+6], s0[8*kj+7]);
        plswap(w0, w2); plswap(w1, w3);
        u32x4 pw = {w0, w1, w2, w3};
        pa[0][kj] = __builtin_bit_cast(bf16x8, pw);
      }
      {
        unsigned w0 = cvtpk(s1[8*kj+0], s1[8*kj+1]);
        unsigned w2 = cvtpk(s1[8*kj+4], s1[8*kj+5]);
        unsigned w1 = cvtpk(s1[8*kj+2], s1[8*kj+3]);
        unsigned w3 = cvtpk(s1[8*kj+6], s1[8*kj+7]);
        plswap(w0, w2); plswap(w1, w3);
        u32x4 pw = {w0, w1, w2, w3};
        pa[1][kj] = __builtin_bit_cast(bf16x8, pw);
      }
    }
    // PV: B = V rows (d = td*32 + l31), contraction over this tile's 32 k
    #pragma unroll
    for (int td = 0; td < 2; ++td)
      #pragma unroll
      for (int kj = 0; kj < 2; ++kj) {
        bf16x8 bv = *(const bf16x8*)(vl + (td*32 + l31) * 64 + ((kj*32 + hi*16) ^ vswz));
        o[0][td] = __builtin_amdgcn_mfma_f32_32x32x16_bf16(pa[0][kj], bv, o[0][td], 0, 0, 0);
        o[1][td] = __builtin_amdgcn_mfma_f32_32x32x16_bf16(pa[1][kj], bv, o[1][td], 0, 0, 0);
      }
  }
  #undef ISSUE
  #undef WRITEB

  // ---- cross-wave reduction (partials are additive: static max) ----
  lp0 += __shfl_xor(lp0, 32);
  lp1 += __shfl_xor(lp1, 32);
  if (hi == 0) {
    Lsl[w][l31]      = lp0;
    Lsl[w][32 + l31] = lp1;
  }
  // each wave writes its partial O into ITS OWN staging region (now dead)
  float* op = (float*)SKV + w * 4096;   // [q 64][d 64]
  #pragma unroll
  for (int qg = 0; qg < 2; ++qg)
    #pragma unroll
    for (int td = 0; td < 2; ++td)
      #pragma unroll
      for (int r = 0; r < 16; ++r) {
        int q = qg*32 + (r & 3) + 8*(r >> 2) + 4*hi;
        op[q * 64 + td*32 + l31] = o[qg][td][r];
      }
  __syncthreads();

  // cooperative sum + normalize + store: thread -> q = tid>>2, 16 d-cols
  {
    const int q   = tid >> 2;
    const int d0  = (tid & 3) * 16;
    const float* ob = (const float*)SKV;
    f32x4 sum[4];
    #pragma unroll
    for (int c = 0; c < 4; ++c) sum[c] = *(const f32x4*)(ob + q*64 + d0 + c*4);
    #pragma unroll
    for (int wv = 1; wv < 4; ++wv)
      #pragma unroll
      for (int c = 0; c < 4; ++c) {
        f32x4 t = *(const f32x4*)(ob + wv*4096 + q*64 + d0 + c*4);
        sum[c] += t;
      }
    float linv = 1.0f / (Lsl[0][q] + Lsl[1][q] + Lsl[2][q] + Lsl[3][q]);
    unsigned pk[8];
    #pragma unroll
    for (int c = 0; c < 4; ++c) {
      pk[c*2]   = cvtpk(sum[c][0] * linv, sum[c][1] * linv);
      pk[c*2+1] = cvtpk(sum[c][2] * linv, sum[c][3] * linv);
    }
    size_t row = (size_t)b * 2048 + q0 + q;
    short* dst = AO + row * 512 + h * 64 + d0;
    *(uint4*)(dst)     = make_uint4(pk[0], pk[1], pk[2], pk[3]);
    *(uint4*)(dst + 8) = make_uint4(pk[4], pk[5], pk[6], pk[7]);
  }
}

extern "C" void kernel_launch(void* const* d_in, const int* in_sizes, int n_in,
                              void* d_out, int out_size, void* d_ws, size_t ws_size,
                              hipStream_t stream)
{
  const float* x     = (const float*)d_in[0];   // [4,2048,512] fp32
  const float* w_qkv = (const float*)d_in[1];   // [1536,512]  fp32
  const float* w_out = (const float*)d_in[2];   // [512,512]   fp32
  const float* temp  = (const float*)d_in[3];   // [8,1,1]     fp32
  float* out = (float*)d_out;
  short* ws  = (short*)d_ws;

  const size_t NQ = (size_t)4 * 8 * 2048 * 64;  // 4194304
  short* Qb   = ws;            // bf16 [b,h,n,64]
  short* Kb   = ws + NQ;       // bf16 [b,h,n,64]
  short* Vtb  = ws + 2 * NQ;   // bf16 [b,h,64,n]
  short* AO16 = ws + 3 * NQ;   // bf16 [8192,512] attention out (after attn)
  short* xb   = ws + 4 * NQ;   // bf16 x (live during gemm_qkv)
  short* wb   = AO16;          // bf16 w_qkv — dead before attn writes AO
  short* wob  = xb;            // bf16 w_out — cvt'd after gemm_qkv (xb dead)

  cvt_f32_bf16<<<dim3(2048), 256, 0, stream>>>(x, xb, 524288);
  cvt_f32_bf16<<<dim3(384),  256, 0, stream>>>(w_qkv, wb, 98304);
  gemm_qkv<<<dim3(12, 64), 256, 0, stream>>>(xb, wb, Qb, Kb, Vtb, temp);
  cvt_f32_bf16<<<dim3(128),  256, 0, stream>>>(w_out, wob, 32768);
  attn_fwd<<<dim3(32, 32), 256, 0, stream>>>(Qb, Kb, Vtb, AO16, temp);
  gemm_out<<<dim3(8, 64), 256, 0, stream>>>(AO16, wob, out);
}

// Round 12
// 92.810 us; speedup vs baseline: 1.0715x; 1.0715x over previous
//
#include <hip/hip_runtime.h>
#include <hip/hip_bf16.h>

using bf16x8 = __attribute__((ext_vector_type(8))) short;
using f32x4  = __attribute__((ext_vector_type(4))) float;
using f32x16 = __attribute__((ext_vector_type(16))) float;
using u32x4  = __attribute__((ext_vector_type(4))) unsigned;

__device__ __forceinline__ short f2bf(float f) {
  union { float f; unsigned u; } v; v.f = f;
  unsigned r = (v.u + 0x7FFFu + ((v.u >> 16) & 1u)) >> 16;
  return (short)(unsigned short)r;
}

__device__ __forceinline__ unsigned cvtpk(float lo, float hi) {
  unsigned r;
  asm("v_cvt_pk_bf16_f32 %0, %1, %2" : "=v"(r) : "v"(lo), "v"(hi));
  return r;
}

__device__ __forceinline__ void plswap(unsigned &a, unsigned &b) {
  asm("v_permlane32_swap_b32 %0, %1" : "+v"(a), "+v"(b));
}

#define GLLDS(gp, lp) __builtin_amdgcn_global_load_lds(                        \
    (const __attribute__((address_space(1))) void*)(gp),                       \
    (__attribute__((address_space(3))) void*)(lp), 16, 0, 0)

// ---------------- fused fp32 -> bf16 conversion: x and w_qkv ---------------
__global__ __launch_bounds__(256)
void cvt_xw(const float* __restrict__ x, const float* __restrict__ wq,
            short* __restrict__ xb, short* __restrict__ wb)
{
  const int blk = blockIdx.x;
  const float* src;
  short* dst;
  int i;
  if (blk < 2048) { src = x;  dst = xb; i = blk * 256 + threadIdx.x; }
  else            { src = wq; dst = wb; i = (blk - 2048) * 256 + threadIdx.x; }
  float4 lo = *(const float4*)(src + (size_t)i * 8);
  float4 hi = *(const float4*)(src + (size_t)i * 8 + 4);
  uint4 r;
  r.x = cvtpk(lo.x, lo.y);
  r.y = cvtpk(lo.z, lo.w);
  r.z = cvtpk(hi.x, hi.y);
  r.w = cvtpk(hi.z, hi.w);
  *(uint4*)(dst + (size_t)i * 8) = r;
}

// ---------------- small fp32 -> bf16 conversion (w_out) --------------------
__global__ __launch_bounds__(256)
void cvt_f32_bf16(const float* __restrict__ in, short* __restrict__ out, int n8)
{
  int i = blockIdx.x * 256 + threadIdx.x;
  if (i >= n8) return;
  float4 lo = *(const float4*)(in + (size_t)i * 8);
  float4 hi = *(const float4*)(in + (size_t)i * 8 + 4);
  uint4 r;
  r.x = cvtpk(lo.x, lo.y);
  r.y = cvtpk(lo.z, lo.w);
  r.z = cvtpk(hi.x, hi.y);
  r.w = cvtpk(hi.z, hi.w);
  *(uint4*)(out + (size_t)i * 8) = r;
}

// ---------------- QKV projection (proven round-7 structure) ----------------
__global__ __launch_bounds__(256, 2)
void gemm_qkv(const short* __restrict__ A, const short* __restrict__ B,
              short* __restrict__ outQ, short* __restrict__ outK,
              short* __restrict__ outVt, const float* __restrict__ temp)
{
  __shared__ short As[128 * 32];
  __shared__ short Bs[128 * 32];
  const int Kd = 512;
  const int tid  = threadIdx.x;
  const int lane = tid & 63;
  const int w    = tid >> 6;
  const int wr   = w >> 1, wc = w & 1;
  const int fr   = lane & 15, fq = lane >> 4;
  const int bm = blockIdx.y, bn = blockIdx.x;
  const int rowA = bm * 128, rowB = bn * 128;

  const int lrow   = lane >> 2;
  const int lchunk = ((lane & 3) ^ ((lane >> 3) & 3)) * 8;
  const short* gA0 = A + (size_t)(rowA + w * 32 + lrow) * Kd + lchunk;
  const short* gB0 = B + (size_t)(rowB + w * 32 + lrow) * Kd + lchunk;
  char* lA0 = (char*)As + (w * 32) * 64;
  char* lB0 = (char*)Bs + (w * 32) * 64;
  const int rxor = ((fr >> 1) & 3) << 4;

  f32x4 acc[4][4];
  #pragma unroll
  for (int m = 0; m < 4; ++m)
    #pragma unroll
    for (int n = 0; n < 4; ++n) acc[m][n] = (f32x4){0.f, 0.f, 0.f, 0.f};

  for (int k0 = 0; k0 < Kd; k0 += 32) {
    GLLDS(gA0 + k0,            lA0);
    GLLDS(gA0 + k0 + 16 * Kd,  lA0 + 1024);
    GLLDS(gB0 + k0,            lB0);
    GLLDS(gB0 + k0 + 16 * Kd,  lB0 + 1024);
    __syncthreads();
    bf16x8 afr[4], bfr[4];
    #pragma unroll
    for (int m = 0; m < 4; ++m)
      afr[m] = *(const bf16x8*)((char*)As + (wr*64 + m*16 + fr) * 64 + ((fq*16) ^ rxor));
    #pragma unroll
    for (int n = 0; n < 4; ++n)
      bfr[n] = *(const bf16x8*)((char*)Bs + (wc*64 + n*16 + fr) * 64 + ((fq*16) ^ rxor));
    #pragma unroll
    for (int m = 0; m < 4; ++m)
      #pragma unroll
      for (int n = 0; n < 4; ++n)
        acc[m][n] = __builtin_amdgcn_mfma_f32_16x16x32_bf16(afr[m], bfr[n], acc[m][n], 0, 0, 0);
    __syncthreads();
  }

  const int gc0   = rowB + wc*64;
  const int slice = gc0 >> 6;
  const int t3    = slice >> 3;
  const int h     = slice & 7;
  if (t3 < 2) {
    float scl[4][4];
    const float tval = (t3 == 0) ? temp[h] * 1.44269504088896f : 1.0f;
    #pragma unroll
    for (int m = 0; m < 4; ++m) {
      #pragma unroll
      for (int r = 0; r < 4; ++r) {
        float ss = 0.f;
        #pragma unroll
        for (int n = 0; n < 4; ++n) ss += acc[m][n][r] * acc[m][n][r];
        #pragma unroll
        for (int off = 1; off < 16; off <<= 1) ss += __shfl_xor(ss, off);
        scl[m][r] = tval / fmaxf(sqrtf(ss), 1e-12f);
      }
    }
    short* dst = (t3 == 0) ? outQ : outK;
    #pragma unroll
    for (int m = 0; m < 4; ++m) {
      #pragma unroll
      for (int r = 0; r < 4; ++r) {
        int rg = rowA + wr*64 + m*16 + fq*4 + r;
        int b = rg >> 11, nn = rg & 2047;
        size_t rowoff = ((size_t)(b*8 + h) * 2048 + nn) * 64;
        #pragma unroll
        for (int n = 0; n < 4; ++n)
          dst[rowoff + n*16 + fr] = f2bf(acc[m][n][r] * scl[m][r]);
      }
    }
  } else {
    #pragma unroll
    for (int m = 0; m < 4; ++m) {
      #pragma unroll
      for (int r = 0; r < 4; ++r) {
        int rg = rowA + wr*64 + m*16 + fq*4 + r;
        int b = rg >> 11, nn = rg & 2047;
        #pragma unroll
        for (int n = 0; n < 4; ++n)
          outVt[((size_t)(b*8 + h) * 64 + n*16 + fr) * 2048 + nn] = f2bf(acc[m][n][r]);
      }
    }
  }
}

// ---------------- output projection: 128x64 tiles (2 blocks/CU) ------------
__global__ __launch_bounds__(256, 2)
void gemm_out(const short* __restrict__ A, const short* __restrict__ B,
              float* __restrict__ outC)
{
  __shared__ short As[128 * 32];
  __shared__ short Bs[64 * 32];
  const int Kd = 512, N = 512;
  const int tid  = threadIdx.x;
  const int lane = tid & 63;
  const int w    = tid >> 6;
  const int fr   = lane & 15, fq = lane >> 4;
  const int bm = blockIdx.y, bn = blockIdx.x;
  const int rowA = bm * 128, rowB = bn * 64;

  const int lrow   = lane >> 2;
  const int lchunk = ((lane & 3) ^ ((lane >> 3) & 3)) * 8;
  const short* gA0 = A + (size_t)(rowA + w * 32 + lrow) * Kd + lchunk;
  const short* gB0 = B + (size_t)(rowB + w * 16 + lrow) * Kd + lchunk;
  char* lA0 = (char*)As + (w * 32) * 64;
  char* lB0 = (char*)Bs + (w * 16) * 64;
  const int rxor = ((fr >> 1) & 3) << 4;

  f32x4 acc[2][4];
  #pragma unroll
  for (int m = 0; m < 2; ++m)
    #pragma unroll
    for (int n = 0; n < 4; ++n) acc[m][n] = (f32x4){0.f, 0.f, 0.f, 0.f};

  for (int k0 = 0; k0 < Kd; k0 += 32) {
    GLLDS(gA0 + k0,            lA0);
    GLLDS(gA0 + k0 + 16 * Kd,  lA0 + 1024);
    GLLDS(gB0 + k0,            lB0);
    __syncthreads();
    bf16x8 afr[2], bfr[4];
    #pragma unroll
    for (int m = 0; m < 2; ++m)
      afr[m] = *(const bf16x8*)((char*)As + (w*32 + m*16 + fr) * 64 + ((fq*16) ^ rxor));
    #pragma unroll
    for (int n = 0; n < 4; ++n)
      bfr[n] = *(const bf16x8*)((char*)Bs + (n*16 + fr) * 64 + ((fq*16) ^ rxor));
    #pragma unroll
    for (int m = 0; m < 2; ++m)
      #pragma unroll
      for (int n = 0; n < 4; ++n)
        acc[m][n] = __builtin_amdgcn_mfma_f32_16x16x32_bf16(afr[m], bfr[n], acc[m][n], 0, 0, 0);
    __syncthreads();
  }

  #pragma unroll
  for (int m = 0; m < 2; ++m) {
    int r0 = rowA + w*32 + m*16 + fq*4;
    #pragma unroll
    for (int n = 0; n < 4; ++n) {
      int c = rowB + n*16 + fr;
      #pragma unroll
      for (int r = 0; r < 4; ++r)
        outC[(size_t)(r0 + r) * N + c] = acc[m][n][r];
    }
  }
}

// ---------------- flash attention v3 (round-10 proven) + setprio -----------
// 32x32 MFMA, swapped QK^T, P in registers (cvt_pk + permlane32_swap),
// static-max softmax (Cauchy-Schwarz bound), cooperative double-buffered
// staging, 1 barrier/iter. setprio(1) wraps MFMA clusters (T5: the two
// co-resident blocks' waves are unsynchronized -> arbitration helps).
__global__ __launch_bounds__(256, 2)
void attn_fwd(const short* __restrict__ Q, const short* __restrict__ Kt,
              const short* __restrict__ Vt, short* __restrict__ AO,
              const float* __restrict__ temp)
{
  __shared__ short Kl[2][64 * 64];
  __shared__ short Vl[2][64 * 64];
  __shared__ float Ls[4][32];
  const int tid  = threadIdx.x;
  const int lane = tid & 63;
  const int w    = tid >> 6;
  const int l31  = lane & 31;
  const int hi   = lane >> 5;
  const int bh = blockIdx.x;          // XCD = bh%8
  const int qt = blockIdx.y;
  const int b = bh >> 3, h = bh & 7;
  const size_t base  = (size_t)bh * 2048 * 64;
  const size_t vbase = (size_t)bh * 64 * 2048;
  const int q0 = qt * 128 + w * 32;   // wave's 32 q-rows

  const short* kp = Kt + base;
  const short* vp = Vt + vbase;

  const int srow  = tid >> 3;
  const int scol8 = (tid & 7) * 8;
  const int scolB = (tid & 7) * 16;
  const int sxor  = (srow & 7) << 4;
  const int kswz  = (l31 & 7) << 4;

  bf16x8 stK[2], stV[2];
  #define LOAD_TILE(T)                                                              \
    do { int kt_ = (T) * 64;                                                        \
      stK[0] = *(const bf16x8*)(kp + (size_t)(kt_ + srow)      * 64 + scol8);       \
      stK[1] = *(const bf16x8*)(kp + (size_t)(kt_ + 32 + srow) * 64 + scol8);       \
      stV[0] = *(const bf16x8*)(vp + (size_t)srow        * 2048 + kt_ + scol8);     \
      stV[1] = *(const bf16x8*)(vp + (size_t)(32 + srow) * 2048 + kt_ + scol8);     \
    } while (0)
  #define WRITE_TILE(P_)                                                            \
    do {                                                                            \
      *(bf16x8*)((char*)Kl[P_] + (srow)      * 128 + (scolB ^ sxor)) = stK[0];      \
      *(bf16x8*)((char*)Kl[P_] + (32 + srow) * 128 + (scolB ^ sxor)) = stK[1];      \
      *(bf16x8*)((char*)Vl[P_] + (srow)      * 128 + (scolB ^ sxor)) = stV[0];      \
      *(bf16x8*)((char*)Vl[P_] + (32 + srow) * 128 + (scolB ^ sxor)) = stV[1];      \
    } while (0)

  // Q B-frags: lane holds Q[q0+l31][dj*16 + hi*8 .. +7], dj=0..3
  bf16x8 bq[4];
  #pragma unroll
  for (int dj = 0; dj < 4; ++dj)
    bq[dj] = *(const bf16x8*)(Q + base + (size_t)(q0 + l31) * 64 + dj*16 + hi*8);

  // static softmax max (Cauchy-Schwarz): s <= |temp|*log2e
  const float Mh = fabsf(temp[h]) * 1.44269504088896f;
  f32x16 cinit;
  #pragma unroll
  for (int r = 0; r < 16; ++r) cinit[r] = -Mh;

  f32x16 o[2];
  #pragma unroll
  for (int td = 0; td < 2; ++td)
    #pragma unroll
    for (int r = 0; r < 16; ++r) o[td][r] = 0.f;
  float lp = 0.f;

  LOAD_TILE(0); WRITE_TILE(0);
  LOAD_TILE(1); WRITE_TILE(1);
  LOAD_TILE(2);
  __syncthreads();

  for (int t = 0; t < 32; ++t) {
    const int p = t & 1;
    const char* kl = (const char*)Kl[p];
    const char* vl = (const char*)Vl[p];

    // QK^T swapped 32x32: A = K rows (k = tk*32+l31), B = Q rows (q = l31)
    f32x16 s[2];
    __builtin_amdgcn_s_setprio(1);
    #pragma unroll
    for (int tk = 0; tk < 2; ++tk) {
      f32x16 z = cinit;
      #pragma unroll
      for (int dj = 0; dj < 4; ++dj) {
        bf16x8 ak = *(const bf16x8*)(kl + (tk*32 + l31) * 128 + ((dj*32 + hi*16) ^ kswz));
        z = __builtin_amdgcn_mfma_f32_32x32x16_bf16(ak, bq[dj], z, 0, 0, 0);
      }
      s[tk] = z;
    }
    __builtin_amdgcn_s_setprio(0);
    // P = exp2(s); lane-partial denom
    #pragma unroll
    for (int tk = 0; tk < 2; ++tk)
      #pragma unroll
      for (int r = 0; r < 16; ++r) {
        float pv = __builtin_amdgcn_exp2f(s[tk][r]);
        s[tk][r] = pv;
        lp += pv;
      }
    // PV A-frags in-register: 4 cvt_pk + 2 permlane swaps per k-16 chunk
    bf16x8 pa[4];
    #pragma unroll
    for (int tk = 0; tk < 2; ++tk)
      #pragma unroll
      for (int j = 0; j < 2; ++j) {
        unsigned w0 = cvtpk(s[tk][8*j+0], s[tk][8*j+1]);
        unsigned w2 = cvtpk(s[tk][8*j+4], s[tk][8*j+5]);
        unsigned w1 = cvtpk(s[tk][8*j+2], s[tk][8*j+3]);
        unsigned w3 = cvtpk(s[tk][8*j+6], s[tk][8*j+7]);
        plswap(w0, w2);
        plswap(w1, w3);
        u32x4 pw = {w0, w1, w2, w3};
        pa[tk*2 + j] = __builtin_bit_cast(bf16x8, pw);
      }
    // PV: A = P rows (q = l31), B = V rows (d = td*32+l31)
    __builtin_amdgcn_s_setprio(1);
    #pragma unroll
    for (int td = 0; td < 2; ++td) {
      f32x16 acc = o[td];
      #pragma unroll
      for (int kj = 0; kj < 4; ++kj) {
        bf16x8 bv = *(const bf16x8*)(vl + (td*32 + l31) * 128 + ((kj*32 + hi*16) ^ kswz));
        acc = __builtin_amdgcn_mfma_f32_32x32x16_bf16(pa[kj], bv, acc, 0, 0, 0);
      }
      o[td] = acc;
    }
    __builtin_amdgcn_s_setprio(0);

    if (t < 31) {
      __syncthreads();
      if (t < 30) {
        WRITE_TILE(p);
        if (t < 29) LOAD_TILE(t + 3);
      }
    }
  }
  #undef LOAD_TILE
  #undef WRITE_TILE

  // denom: lanes l31 and l31+32 hold complementary k halves of q=l31
  lp += __shfl_xor(lp, 32);
  if (hi == 0) Ls[w][l31] = 1.0f / lp;   // per-wave region; in-order wave LDS
  #pragma unroll
  for (int td = 0; td < 2; ++td)
    #pragma unroll
    for (int r = 0; r < 16; ++r) {
      int qr = (r & 3) + 8 * (r >> 2) + 4 * hi;   // C/D row (q)
      float li = Ls[w][qr];
      int row = b * 2048 + q0 + qr;
      int col = h * 64 + td * 32 + l31;
      AO[(size_t)row * 512 + col] = f2bf(o[td][r] * li);
    }
}

extern "C" void kernel_launch(void* const* d_in, const int* in_sizes, int n_in,
                              void* d_out, int out_size, void* d_ws, size_t ws_size,
                              hipStream_t stream)
{
  const float* x     = (const float*)d_in[0];   // [4,2048,512] fp32
  const float* w_qkv = (const float*)d_in[1];   // [1536,512]  fp32
  const float* w_out = (const float*)d_in[2];   // [512,512]   fp32
  const float* temp  = (const float*)d_in[3];   // [8,1,1]     fp32
  float* out = (float*)d_out;
  short* ws  = (short*)d_ws;

  const size_t NQ = (size_t)4 * 8 * 2048 * 64;  // 4194304
  short* Qb   = ws;            // bf16 [b,h,n,64]
  short* Kb   = ws + NQ;       // bf16 [b,h,n,64]
  short* Vtb  = ws + 2 * NQ;   // bf16 [b,h,64,n]
  short* AO16 = ws + 3 * NQ;   // bf16 [8192,512] attention out (after attn)
  short* xb   = ws + 4 * NQ;   // bf16 x (live during gemm_qkv)
  short* wb   = AO16;          // bf16 w_qkv — dead before attn writes AO
  short* wob  = xb;            // bf16 w_out — cvt'd after gemm_qkv (xb dead)

  cvt_xw<<<dim3(2432), 256, 0, stream>>>(x, w_qkv, xb, wb);
  gemm_qkv<<<dim3(12, 64), 256, 0, stream>>>(xb, wb, Qb, Kb, Vtb, temp);
  cvt_f32_bf16<<<dim3(128), 256, 0, stream>>>(w_out, wob, 32768);
  attn_fwd<<<dim3(32, 16), 256, 0, stream>>>(Qb, Kb, Vtb, AO16, temp);
  gemm_out<<<dim3(8, 64), 256, 0, stream>>>(AO16, wob, out);
}